// Round 17
// baseline (168.056 us; speedup 1.0000x reference)
//
#include <hip/hip_runtime.h>
#include <hip/hip_bf16.h>

#define D    64    // feature dim == units
#define CH   4096  // edges per chunk (K1/K3)
#define BKT  32    // nodes per bucket (K4)
#define PASS 1024  // edges staged per pass in K4
#define SU   2048  // scan unit size (K2)

// ---------------------------------------------------------------------------
// K1: blocks [0, gemmTiles): Z = emb @ W, stored as TWO bf16 half-matrices
// Zlo=[N][32], Zhi=[N][32] (3.2 MB each — fits per-XCD L2 for the split
// aggregate).  Blocks [gemmTiles, +NC): per-chunk bucket histogram.
// ---------------------------------------------------------------------------
__global__ __launch_bounds__(256) void gemm_part(
    const float* __restrict__ emb,
    const float* __restrict__ W,
    __hip_bfloat16* __restrict__ Zb,   // [2][N][32]
    const int*   __restrict__ dst,
    int*         __restrict__ histG,   // [NB * NC], bucket-major
    int N, int E, int NB, int NC, int gemmTiles)
{
    __shared__ int smem[4096];   // hist[NB<=1563] or 64x64 gemm tile

    if ((int)blockIdx.x >= gemmTiles) {
        const int c   = (int)blockIdx.x - gemmTiles;
        const int t   = threadIdx.x;
        const int e0  = c * CH;
        const int cnt = min(CH, E - e0);          // multiple of 4 (E%4==0)
        for (int b = t; b < NB; b += 256) smem[b] = 0;
        __syncthreads();
        const int4* d4p = reinterpret_cast<const int4*>(dst + e0);
#pragma unroll
        for (int i = 0; i < 4; ++i) {
            int g = i * 256 + t;
            if (g * 4 < cnt) {
                int4 d4 = d4p[g];
                atomicAdd(&smem[d4.x >> 5], 1);
                atomicAdd(&smem[d4.y >> 5], 1);
                atomicAdd(&smem[d4.z >> 5], 1);
                atomicAdd(&smem[d4.w >> 5], 1);
            }
        }
        __syncthreads();
        for (int b = t; b < NB; b += 256)
            histG[(size_t)b * NC + c] = smem[b];
        return;
    }

    const int lane = threadIdx.x & 63;
    const int wave = threadIdx.x >> 6;

    float wcol[D];
#pragma unroll
    for (int k = 0; k < D; ++k) wcol[k] = W[k * D + lane];

    float* At = (float*)smem;
    const int row0 = blockIdx.x * 64;

    for (int i = threadIdx.x; i < 1024; i += 256) {
        int r = i >> 4, gr = row0 + r;
        float4 v = (gr < N)
            ? reinterpret_cast<const float4*>(emb)[(size_t)gr * 16 + (i & 15)]
            : float4{0.f, 0.f, 0.f, 0.f};
        reinterpret_cast<float4*>(At)[i] = v;
    }
    __syncthreads();

    const int half = lane >> 5;             // 0: features 0-31, 1: 32-63
    const int fo   = lane & 31;
    __hip_bfloat16* Zh = Zb + (size_t)half * N * 32;

    for (int rr = 0; rr < 16; ++rr) {
        int r = wave * 16 + rr, gr = row0 + r;
        if (gr >= N) break;
        const float4* arow = reinterpret_cast<const float4*>(At + r * D);
        float acc = 0.f;
#pragma unroll
        for (int k4 = 0; k4 < 16; ++k4) {
            float4 a = arow[k4];
            acc = fmaf(a.x, wcol[4 * k4 + 0], acc);
            acc = fmaf(a.y, wcol[4 * k4 + 1], acc);
            acc = fmaf(a.z, wcol[4 * k4 + 2], acc);
            acc = fmaf(a.w, wcol[4 * k4 + 3], acc);
        }
        Zh[(size_t)gr * 32 + fo] = __float2bfloat16(acc);
    }
}

// ---------------------------------------------------------------------------
// K2: per-unit exclusive scan of bucket-major histG — fully COALESCED.
// ---------------------------------------------------------------------------
__global__ __launch_bounds__(256) void scan_hist(
    const int* __restrict__ histG, int* __restrict__ offsets,
    int* __restrict__ partials, int M)
{
    __shared__ int sh[256];
    const int t    = threadIdx.x;
    const int base = blockIdx.x * SU + t * 8;

    int v[8], ps[8];
#pragma unroll
    for (int k = 0; k < 8; ++k) {
        int m = base + k;
        v[k] = (m < M) ? histG[m] : 0;
    }
    int s = 0;
#pragma unroll
    for (int k = 0; k < 8; ++k) { ps[k] = s; s += v[k]; }
    sh[t] = s;
    __syncthreads();
    for (int off = 1; off < 256; off <<= 1) {
        int x = (t >= off) ? sh[t - off] : 0;
        __syncthreads();
        sh[t] += x;
        __syncthreads();
    }
    const int excl = sh[t] - s;
#pragma unroll
    for (int k = 0; k < 8; ++k)
        offsets[base + k] = excl + ps[k];
    if (t == 255) partials[blockIdx.x] = sh[255];
}

// K2b: ONE block scans the <=256 unit totals IN PLACE (exclusive prefix).
__global__ __launch_bounds__(256) void scan_partials_k(
    int* __restrict__ partials, int units)
{
    __shared__ int sh[256];
    const int t    = threadIdx.x;
    const int orig = (t < units) ? partials[t] : 0;
    sh[t] = orig;
    __syncthreads();
    for (int off = 1; off < 256; off <<= 1) {
        int x = (t >= off) ? sh[t - off] : 0;
        __syncthreads();
        sh[t] += x;
        __syncthreads();
    }
    if (t < units) partials[t] = sh[t] - orig;   // exclusive
}

// ---------------------------------------------------------------------------
// K3: bucket-grouped scatter (round-15 proven config: 256 thr x 16 edges).
// rec.x = src(16) | dl(5)<<16 | bkt(11)<<21   (N<65536, NB<2048).
// ---------------------------------------------------------------------------
__global__ __launch_bounds__(256) void scatter_bkt(
    const int*   __restrict__ src,
    const int*   __restrict__ dst,
    const float* __restrict__ w,
    const int*   __restrict__ offsets,
    const int*   __restrict__ partials,   // exclusive prefix (global)
    int2*        __restrict__ csr,
    int E, int NB, int NC)
{
    __shared__ int2 rec[CH];       // 32 KB
    __shared__ int  lcnt[1568];    // 6.3 KB
    __shared__ int  sh[256];

    const int t   = threadIdx.x;
    const int c   = blockIdx.x;
    const int e0  = c * CH;
    const int cnt = min(CH, E - e0);   // multiple of 4

    for (int b = t; b < NB; b += 256) lcnt[b] = 0;
    __syncthreads();

    int2 myrec[16]; int mypos[16];
    const int4*   s4p = reinterpret_cast<const int4*>(src + e0);
    const int4*   d4p = reinterpret_cast<const int4*>(dst + e0);
    const float4* w4p = reinterpret_cast<const float4*>(w + e0);
#pragma unroll
    for (int i = 0; i < 4; ++i) {
        int g = i * 256 + t;
        if (g * 4 < cnt) {
            int4   s4 = s4p[g];
            int4   d4 = d4p[g];
            float4 w4 = w4p[g];
            int b0 = d4.x >> 5, b1 = d4.y >> 5, b2 = d4.z >> 5, b3 = d4.w >> 5;
            myrec[4*i+0] = make_int2(s4.x | ((d4.x & 31) << 16) | (b0 << 21), __float_as_int(w4.x));
            myrec[4*i+1] = make_int2(s4.y | ((d4.y & 31) << 16) | (b1 << 21), __float_as_int(w4.y));
            myrec[4*i+2] = make_int2(s4.z | ((d4.z & 31) << 16) | (b2 << 21), __float_as_int(w4.z));
            myrec[4*i+3] = make_int2(s4.w | ((d4.w & 31) << 16) | (b3 << 21), __float_as_int(w4.w));
            mypos[4*i+0] = atomicAdd(&lcnt[b0], 1);
            mypos[4*i+1] = atomicAdd(&lcnt[b1], 1);
            mypos[4*i+2] = atomicAdd(&lcnt[b2], 1);
            mypos[4*i+3] = atomicAdd(&lcnt[b3], 1);
        } else {
#pragma unroll
            for (int k = 0; k < 4; ++k) mypos[4*i+k] = -1;
        }
    }
    __syncthreads();

    int hv[7], ps[7];
    const int hbase = t * 7;
#pragma unroll
    for (int k = 0; k < 7; ++k) {
        int b = hbase + k;
        hv[k] = (b < NB) ? lcnt[b] : 0;
    }
    int s = 0;
#pragma unroll
    for (int k = 0; k < 7; ++k) { ps[k] = s; s += hv[k]; }
    sh[t] = s;
    __syncthreads();
    for (int off = 1; off < 256; off <<= 1) {
        int x = (t >= off) ? sh[t - off] : 0;
        __syncthreads();
        sh[t] += x;
        __syncthreads();
    }
    const int hexcl = sh[t] - s;
    __syncthreads();
#pragma unroll
    for (int k = 0; k < 7; ++k) {
        int b = hbase + k;
        if (b < NB) lcnt[b] = hexcl + ps[k];   // localBase
    }
    __syncthreads();

#pragma unroll
    for (int k = 0; k < 16; ++k) {
        if (mypos[k] >= 0)
            rec[lcnt[(unsigned)myrec[k].x >> 21] + mypos[k]] = myrec[k];
    }
    __syncthreads();

#pragma unroll
    for (int k = 0; k < 7; ++k) {
        int b = hbase + k;
        if (b < NB) {
            int m = b * NC + c;
            lcnt[b] = offsets[m] + partials[m >> 11] - lcnt[b];
        }
    }
    __syncthreads();

    for (int j = t; j < cnt; j += 256) {
        int2 rj = rec[j];
        csr[j + lcnt[(unsigned)rj.x >> 21]] = rj;
    }
}

// ---------------------------------------------------------------------------
// K4: per-bucket aggregate over ONE 32-feature half.  Launched twice (h=0,1);
// per-dispatch gather working set = 3.2 MB -> per-XCD-L2 resident.
// 16 slots x 4 q-lanes: 16 independent 64 B row chains per wave.
// ---------------------------------------------------------------------------
__global__ __launch_bounds__(256) void aggregate_half(
    const __hip_bfloat16* __restrict__ Zh,   // [N][32] bf16 half-matrix
    const int2* __restrict__ csr,
    const int*  __restrict__ offsets,
    const int*  __restrict__ partials,   // exclusive prefix (global)
    float*      __restrict__ out,
    int N, int NB, int NC, int h)
{
    __shared__ int2 srec[PASS];   // 8 KB
    __shared__ int  hist[BKT];
    __shared__ int  nbase[BKT + 1];

    const int t = threadIdx.x;
    const int b = blockIdx.x;

    const int m0 = b * NC, m1 = m0 + NC;
    const int bStart = offsets[m0] + partials[m0 >> 11];
    const int bEnd   = offsets[m1] + partials[m1 >> 11];

    const int wv = t >> 6, lane = t & 63;
    const int slot = lane >> 2;   // 0..15
    const int q    = lane & 3;    // 0..3 — int4 within the 64 B half-row
    const int4* Zq = reinterpret_cast<const int4*>(Zh);   // half row = 4 int4

    float4 alo[8], ahi[8];
#pragma unroll
    for (int r = 0; r < 8; ++r) { alo[r] = float4{0,0,0,0}; ahi[r] = float4{0,0,0,0}; }

#define FMA8(LO, HI, WW, ZZ)                                                     \
    do {                                                                         \
        (LO).x = fmaf((WW), __uint_as_float((unsigned)(ZZ).x << 16),        (LO).x); \
        (LO).y = fmaf((WW), __uint_as_float((unsigned)(ZZ).x & 0xFFFF0000u),(LO).y); \
        (LO).z = fmaf((WW), __uint_as_float((unsigned)(ZZ).y << 16),        (LO).z); \
        (LO).w = fmaf((WW), __uint_as_float((unsigned)(ZZ).y & 0xFFFF0000u),(LO).w); \
        (HI).x = fmaf((WW), __uint_as_float((unsigned)(ZZ).z << 16),        (HI).x); \
        (HI).y = fmaf((WW), __uint_as_float((unsigned)(ZZ).z & 0xFFFF0000u),(HI).y); \
        (HI).z = fmaf((WW), __uint_as_float((unsigned)(ZZ).w << 16),        (HI).z); \
        (HI).w = fmaf((WW), __uint_as_float((unsigned)(ZZ).w & 0xFFFF0000u),(HI).w); \
    } while (0)

    for (int cur = bStart; cur < bEnd; cur += PASS) {
        const int cnt = min(PASS, bEnd - cur);
        if (t < BKT) hist[t] = 0;
        __syncthreads();

        int2 myrec[4]; int mypos[4];
#pragma unroll
        for (int k = 0; k < 4; ++k) {
            int j = k * 256 + t;
            if (j < cnt) {
                int2 r2 = csr[cur + j];
                myrec[k] = r2;
                mypos[k] = atomicAdd(&hist[(r2.x >> 16) & (BKT - 1)], 1);
            } else mypos[k] = -1;
        }
        __syncthreads();

        if (t < BKT) {
            int v = hist[t], x = v;
            for (int off = 1; off < BKT; off <<= 1) {
                int y = __shfl_up(x, off, 64);
                if (t >= off) x += y;
            }
            nbase[t] = x - v;
            if (t == BKT - 1) nbase[BKT] = x;
        }
        __syncthreads();

#pragma unroll
        for (int k = 0; k < 4; ++k) {
            if (mypos[k] >= 0)
                srec[nbase[(myrec[k].x >> 16) & (BKT - 1)] + mypos[k]] = myrec[k];
        }
        __syncthreads();

        // gather: wave wv owns nodes [wv*8, wv*8+8); 16 slots, 2-deep prefetch
        for (int r = 0; r < 8; ++r) {
            const int nl = wv * 8 + r;
            const int jb = nbase[nl] + slot;
            const int je = nbase[nl + 1];
            const int j1 = jb + 16;
            int2 e0 = make_int2(0, 0), e1 = make_int2(0, 0);
            if (jb < je) e0 = srec[jb];
            if (j1 < je) e1 = srec[j1];
            int4 z0 = make_int4(0,0,0,0), z1 = make_int4(0,0,0,0);
            if (jb < je) z0 = Zq[(size_t)(e0.x & 0xFFFF) * 4 + q];
            if (j1 < je) z1 = Zq[(size_t)(e1.x & 0xFFFF) * 4 + q];
            FMA8(alo[r], ahi[r], __int_as_float(e0.y), z0);
            FMA8(alo[r], ahi[r], __int_as_float(e1.y), z1);
            for (int j = j1 + 16; j < je; j += 16) {   // tail (deg > 32)
                int2 e = srec[j];
                int4 zz = Zq[(size_t)(e.x & 0xFFFF) * 4 + q];
                FMA8(alo[r], ahi[r], __int_as_float(e.y), zz);
            }
        }
        __syncthreads();
    }

    // reduce the 16 slots + store (4 lanes x 32 B = coalesced 128 B half-row)
    const int node0 = b * BKT + wv * 8;
#pragma unroll
    for (int r = 0; r < 8; ++r) {
        float4 lo = alo[r], hi = ahi[r];
#pragma unroll
        for (int off = 32; off >= 4; off >>= 1) {
            lo.x += __shfl_down(lo.x, off, 64);
            lo.y += __shfl_down(lo.y, off, 64);
            lo.z += __shfl_down(lo.z, off, 64);
            lo.w += __shfl_down(lo.w, off, 64);
            hi.x += __shfl_down(hi.x, off, 64);
            hi.y += __shfl_down(hi.y, off, 64);
            hi.z += __shfl_down(hi.z, off, 64);
            hi.w += __shfl_down(hi.w, off, 64);
        }
        int node = node0 + r;
        if (lane < 4 && node < N) {
            float4 o0, o1;
            o0.x = fmaxf(lo.x, 0.f); o0.y = fmaxf(lo.y, 0.f);
            o0.z = fmaxf(lo.z, 0.f); o0.w = fmaxf(lo.w, 0.f);
            o1.x = fmaxf(hi.x, 0.f); o1.y = fmaxf(hi.y, 0.f);
            o1.z = fmaxf(hi.z, 0.f); o1.w = fmaxf(hi.w, 0.f);
            // features h*32 + lane*8 .. +8 of node's 64-float row
            float4* orow = reinterpret_cast<float4*>(out)
                         + (size_t)node * 16 + h * 8 + lane * 2;
            orow[0] = o0;
            orow[1] = o1;
        }
    }
#undef FMA8
}

// ---------------------------------------------------------------------------
extern "C" void kernel_launch(void* const* d_in, const int* in_sizes, int n_in,
                              void* d_out, int out_size, void* d_ws, size_t ws_size,
                              hipStream_t stream)
{
    const float* emb  = (const float*)d_in[0];  // [N, 64]
    const int*   esrc = (const int*)  d_in[1];  // [E]
    const int*   edst = (const int*)  d_in[2];  // [E]
    const float* ew   = (const float*)d_in[3];  // [E]
    const float* W    = (const float*)d_in[4];  // [64, 64]
    float*       out  = (float*)d_out;          // [N, 64]

    const int N = in_sizes[0] / D;
    const int E = in_sizes[1];

    const int NB    = (N + BKT - 1) / BKT;   // 1563 buckets
    const int NC    = (E + CH - 1) / CH;     // 196 chunks
    const int M     = NB * NC;               // 306,348
    const int units = (M + SU - 1) / SU;     // 150 <= 256
    const int Mpad  = units * SU;
    const int gemmTiles = (N + 63) / 64;     // 782

    // Workspace (~15.2 MB), all segments 16 B aligned.
    char* p = (char*)d_ws;
    __hip_bfloat16* Zb = (__hip_bfloat16*)p;  p += (size_t)N * D * 2;   // 6.4 MB (2 halves)
    int*  histG    = (int*)p;                 p += (size_t)Mpad * 4;    // 1.2 MB
    int*  offsets  = (int*)p;                 p += (size_t)Mpad * 4;    // 1.2 MB
    int*  partials = (int*)p;                 p += 256 * 4;
    int2* csr      = (int2*)p;                                          // 6.4 MB

    gemm_part<<<gemmTiles + NC, 256, 0, stream>>>(
        emb, W, Zb, edst, histG, N, E, NB, NC, gemmTiles);

    scan_hist<<<units, 256, 0, stream>>>(histG, offsets, partials, M);

    scan_partials_k<<<1, 256, 0, stream>>>(partials, units);

    scatter_bkt<<<NC, 256, 0, stream>>>(
        esrc, edst, ew, offsets, partials, csr, E, NB, NC);

    aggregate_half<<<NB, 256, 0, stream>>>(
        Zb, csr, offsets, partials, out, N, NB, NC, 0);

    aggregate_half<<<NB, 256, 0, stream>>>(
        Zb + (size_t)N * 32, csr, offsets, partials, out, N, NB, NC, 1);
}

// Round 18
// 137.522 us; speedup vs baseline: 1.2220x; 1.2220x over previous
//
#include <hip/hip_runtime.h>
#include <hip/hip_bf16.h>

#define D    64    // feature dim == units
#define CH   4096  // edges per chunk (K1/K3)
#define BKT  32    // nodes per bucket (K4)
#define PASS 1024  // edges staged per pass in K4
#define SU   2048  // scan unit size (K2)

// ---------------------------------------------------------------------------
// K1: blocks [0, gemmTiles): Z = emb @ W (bf16 out).  Blocks [gemmTiles, +NC):
// per-chunk bucket histogram (LDS int atomics, no return), written BUCKET-
// MAJOR (histG[b*NC+c], scattered 4B fire-and-forget) so K2 reads coalesced.
// ---------------------------------------------------------------------------
__global__ __launch_bounds__(256) void gemm_part(
    const float* __restrict__ emb,
    const float* __restrict__ W,
    __hip_bfloat16* __restrict__ Zb,
    const int*   __restrict__ dst,
    int*         __restrict__ histG,   // [NB * NC], bucket-major
    int N, int E, int NB, int NC, int gemmTiles)
{
    __shared__ int smem[4096];   // hist[NB<=1563] or 64x64 gemm tile

    if ((int)blockIdx.x >= gemmTiles) {
        const int c   = (int)blockIdx.x - gemmTiles;
        const int t   = threadIdx.x;
        const int e0  = c * CH;
        const int cnt = min(CH, E - e0);          // multiple of 4 (E%4==0)
        for (int b = t; b < NB; b += 256) smem[b] = 0;
        __syncthreads();
        const int4* d4p = reinterpret_cast<const int4*>(dst + e0);
#pragma unroll
        for (int i = 0; i < 4; ++i) {
            int g = i * 256 + t;
            if (g * 4 < cnt) {
                int4 d4 = d4p[g];
                atomicAdd(&smem[d4.x >> 5], 1);
                atomicAdd(&smem[d4.y >> 5], 1);
                atomicAdd(&smem[d4.z >> 5], 1);
                atomicAdd(&smem[d4.w >> 5], 1);
            }
        }
        __syncthreads();
        for (int b = t; b < NB; b += 256)
            histG[(size_t)b * NC + c] = smem[b];
        return;
    }

    const int lane = threadIdx.x & 63;
    const int wave = threadIdx.x >> 6;

    float wcol[D];
#pragma unroll
    for (int k = 0; k < D; ++k) wcol[k] = W[k * D + lane];

    float* At = (float*)smem;
    const int row0 = blockIdx.x * 64;

    for (int i = threadIdx.x; i < 1024; i += 256) {
        int r = i >> 4, gr = row0 + r;
        float4 v = (gr < N)
            ? reinterpret_cast<const float4*>(emb)[(size_t)gr * 16 + (i & 15)]
            : float4{0.f, 0.f, 0.f, 0.f};
        reinterpret_cast<float4*>(At)[i] = v;
    }
    __syncthreads();

    for (int rr = 0; rr < 16; ++rr) {
        int r = wave * 16 + rr, gr = row0 + r;
        if (gr >= N) break;
        const float4* arow = reinterpret_cast<const float4*>(At + r * D);
        float acc = 0.f;
#pragma unroll
        for (int k4 = 0; k4 < 16; ++k4) {
            float4 a = arow[k4];
            acc = fmaf(a.x, wcol[4 * k4 + 0], acc);
            acc = fmaf(a.y, wcol[4 * k4 + 1], acc);
            acc = fmaf(a.z, wcol[4 * k4 + 2], acc);
            acc = fmaf(a.w, wcol[4 * k4 + 3], acc);
        }
        Zb[(size_t)gr * D + lane] = __float2bfloat16(acc);
    }
}

// ---------------------------------------------------------------------------
// K2: per-unit exclusive scan of bucket-major histG — fully COALESCED.
// SU=2048 elems/block (256 thr x 8); unit totals to partials (<=256).
// ---------------------------------------------------------------------------
__global__ __launch_bounds__(256) void scan_hist(
    const int* __restrict__ histG, int* __restrict__ offsets,
    int* __restrict__ partials, int M)
{
    __shared__ int sh[256];
    const int t    = threadIdx.x;
    const int base = blockIdx.x * SU + t * 8;

    int v[8], ps[8];
#pragma unroll
    for (int k = 0; k < 8; ++k) {
        int m = base + k;
        v[k] = (m < M) ? histG[m] : 0;
    }
    int s = 0;
#pragma unroll
    for (int k = 0; k < 8; ++k) { ps[k] = s; s += v[k]; }
    sh[t] = s;
    __syncthreads();
    for (int off = 1; off < 256; off <<= 1) {
        int x = (t >= off) ? sh[t - off] : 0;
        __syncthreads();
        sh[t] += x;
        __syncthreads();
    }
    const int excl = sh[t] - s;
#pragma unroll
    for (int k = 0; k < 8; ++k)
        offsets[base + k] = excl + ps[k];
    if (t == 255) partials[blockIdx.x] = sh[255];
}

// ---------------------------------------------------------------------------
// K2b: ONE block scans the <=256 unit totals IN PLACE (exclusive prefix).
// Downstream kernels read partials[] directly — no per-block re-scan.
// ---------------------------------------------------------------------------
__global__ __launch_bounds__(256) void scan_partials_k(
    int* __restrict__ partials, int units)
{
    __shared__ int sh[256];
    const int t    = threadIdx.x;
    const int orig = (t < units) ? partials[t] : 0;
    sh[t] = orig;
    __syncthreads();
    for (int off = 1; off < 256; off <<= 1) {
        int x = (t >= off) ? sh[t - off] : 0;
        __syncthreads();
        sh[t] += x;
        __syncthreads();
    }
    if (t < units) partials[t] = sh[t] - orig;   // exclusive
}

// ---------------------------------------------------------------------------
// K3: bucket-grouped scatter.  Recounts its chunk with ds_add_rtn, stages
// records sorted by bucket in LDS, writes runs.  Reads the GLOBAL partials
// prefix (K2b) — no local partials scan.
// rec.x = src(16) | dl(5)<<16 | bkt(11)<<21   (N<65536, NB<2048).
// ---------------------------------------------------------------------------
__global__ __launch_bounds__(256) void scatter_bkt(
    const int*   __restrict__ src,
    const int*   __restrict__ dst,
    const float* __restrict__ w,
    const int*   __restrict__ offsets,
    const int*   __restrict__ partials,   // exclusive prefix (global)
    int2*        __restrict__ csr,
    int E, int NB, int NC)
{
    __shared__ int2 rec[CH];       // 32 KB
    __shared__ int  lcnt[1568];    // 6.3 KB
    __shared__ int  sh[256];

    const int t   = threadIdx.x;
    const int c   = blockIdx.x;
    const int e0  = c * CH;
    const int cnt = min(CH, E - e0);   // multiple of 4

    for (int b = t; b < NB; b += 256) lcnt[b] = 0;
    __syncthreads();

    // load + count-with-return (16 edges/thread, vector loads)
    int2 myrec[16]; int mypos[16];
    const int4*   s4p = reinterpret_cast<const int4*>(src + e0);
    const int4*   d4p = reinterpret_cast<const int4*>(dst + e0);
    const float4* w4p = reinterpret_cast<const float4*>(w + e0);
#pragma unroll
    for (int i = 0; i < 4; ++i) {
        int g = i * 256 + t;
        if (g * 4 < cnt) {
            int4   s4 = s4p[g];
            int4   d4 = d4p[g];
            float4 w4 = w4p[g];
            int b0 = d4.x >> 5, b1 = d4.y >> 5, b2 = d4.z >> 5, b3 = d4.w >> 5;
            myrec[4*i+0] = make_int2(s4.x | ((d4.x & 31) << 16) | (b0 << 21), __float_as_int(w4.x));
            myrec[4*i+1] = make_int2(s4.y | ((d4.y & 31) << 16) | (b1 << 21), __float_as_int(w4.y));
            myrec[4*i+2] = make_int2(s4.z | ((d4.z & 31) << 16) | (b2 << 21), __float_as_int(w4.z));
            myrec[4*i+3] = make_int2(s4.w | ((d4.w & 31) << 16) | (b3 << 21), __float_as_int(w4.w));
            mypos[4*i+0] = atomicAdd(&lcnt[b0], 1);
            mypos[4*i+1] = atomicAdd(&lcnt[b1], 1);
            mypos[4*i+2] = atomicAdd(&lcnt[b2], 1);
            mypos[4*i+3] = atomicAdd(&lcnt[b3], 1);
        } else {
#pragma unroll
            for (int k = 0; k < 4; ++k) mypos[4*i+k] = -1;
        }
    }
    __syncthreads();

    // local exclusive scan of lcnt (7 buckets/thread covers 1792 >= NB)
    int hv[7], ps[7];
    const int hbase = t * 7;
#pragma unroll
    for (int k = 0; k < 7; ++k) {
        int b = hbase + k;
        hv[k] = (b < NB) ? lcnt[b] : 0;
    }
    int s = 0;
#pragma unroll
    for (int k = 0; k < 7; ++k) { ps[k] = s; s += hv[k]; }
    sh[t] = s;
    __syncthreads();
    for (int off = 1; off < 256; off <<= 1) {
        int x = (t >= off) ? sh[t - off] : 0;
        __syncthreads();
        sh[t] += x;
        __syncthreads();
    }
    const int hexcl = sh[t] - s;
    __syncthreads();                       // all reads of lcnt done
#pragma unroll
    for (int k = 0; k < 7; ++k) {
        int b = hbase + k;
        if (b < NB) lcnt[b] = hexcl + ps[k];   // localBase
    }
    __syncthreads();

    // stage records sorted by bucket
#pragma unroll
    for (int k = 0; k < 16; ++k) {
        if (mypos[k] >= 0)
            rec[lcnt[(unsigned)myrec[k].x >> 21] + mypos[k]] = myrec[k];
    }
    __syncthreads();

    // lcnt[b] := globalChunkOff(b,c) - localBase[b]   (global partials read)
#pragma unroll
    for (int k = 0; k < 7; ++k) {
        int b = hbase + k;
        if (b < NB) {
            int m = b * NC + c;
            lcnt[b] = offsets[m] + partials[m >> 11] - lcnt[b];
        }
    }
    __syncthreads();

    for (int j = t; j < cnt; j += 256) {
        int2 rj = rec[j];
        csr[j + lcnt[(unsigned)rj.x >> 21]] = rj;
    }
}

// ---------------------------------------------------------------------------
// K4: one block per 32-node bucket.  Bucket bounds come from the GLOBAL
// offsets+partials (no local scan).  Sort pass edges by node in LDS (int
// atomics + shfl scan), then register-gather with 3-deep per-slot prefetch.
// ---------------------------------------------------------------------------
__global__ __launch_bounds__(256) void aggregate(
    const __hip_bfloat16* __restrict__ Zb,
    const int2* __restrict__ csr,
    const int*  __restrict__ offsets,
    const int*  __restrict__ partials,   // exclusive prefix (global)
    float*      __restrict__ out,
    int N, int NB, int NC)
{
    __shared__ int2 srec[PASS];   // 8 KB
    __shared__ int  hist[BKT];
    __shared__ int  nbase[BKT + 1];

    const int t = threadIdx.x;
    const int b = blockIdx.x;

    const int m0 = b * NC, m1 = m0 + NC;
    const int bStart = offsets[m0] + partials[m0 >> 11];
    const int bEnd   = offsets[m1] + partials[m1 >> 11];

    const int wv = t >> 6, lane = t & 63, slot = lane >> 3, q = lane & 7;
    const int4* Zq = reinterpret_cast<const int4*>(Zb);   // bf16 row = 8 int4

    float4 alo[8], ahi[8];
#pragma unroll
    for (int r = 0; r < 8; ++r) { alo[r] = float4{0,0,0,0}; ahi[r] = float4{0,0,0,0}; }

#define FMA8(LO, HI, WW, ZZ)                                                     \
    do {                                                                         \
        (LO).x = fmaf((WW), __uint_as_float((unsigned)(ZZ).x << 16),        (LO).x); \
        (LO).y = fmaf((WW), __uint_as_float((unsigned)(ZZ).x & 0xFFFF0000u),(LO).y); \
        (LO).z = fmaf((WW), __uint_as_float((unsigned)(ZZ).y << 16),        (LO).z); \
        (LO).w = fmaf((WW), __uint_as_float((unsigned)(ZZ).y & 0xFFFF0000u),(LO).w); \
        (HI).x = fmaf((WW), __uint_as_float((unsigned)(ZZ).z << 16),        (HI).x); \
        (HI).y = fmaf((WW), __uint_as_float((unsigned)(ZZ).z & 0xFFFF0000u),(HI).y); \
        (HI).z = fmaf((WW), __uint_as_float((unsigned)(ZZ).w << 16),        (HI).z); \
        (HI).w = fmaf((WW), __uint_as_float((unsigned)(ZZ).w & 0xFFFF0000u),(HI).w); \
    } while (0)

    for (int cur = bStart; cur < bEnd; cur += PASS) {
        const int cnt = min(PASS, bEnd - cur);
        if (t < BKT) hist[t] = 0;
        __syncthreads();

        int2 myrec[4]; int mypos[4];
#pragma unroll
        for (int k = 0; k < 4; ++k) {
            int j = k * 256 + t;
            if (j < cnt) {
                int2 r2 = csr[cur + j];
                myrec[k] = r2;
                mypos[k] = atomicAdd(&hist[(r2.x >> 16) & (BKT - 1)], 1);
            } else mypos[k] = -1;
        }
        __syncthreads();

        if (t < BKT) {
            int v = hist[t], x = v;
            for (int off = 1; off < BKT; off <<= 1) {
                int y = __shfl_up(x, off, 64);
                if (t >= off) x += y;
            }
            nbase[t] = x - v;
            if (t == BKT - 1) nbase[BKT] = x;
        }
        __syncthreads();

#pragma unroll
        for (int k = 0; k < 4; ++k) {
            if (mypos[k] >= 0)
                srec[nbase[(myrec[k].x >> 16) & (BKT - 1)] + mypos[k]] = myrec[k];
        }
        __syncthreads();

        // gather: wave wv owns nodes [wv*8, wv*8+8), 3-deep prefetched
        for (int r = 0; r < 8; ++r) {
            const int nl = wv * 8 + r;
            const int jb = nbase[nl] + slot;
            const int je = nbase[nl + 1];
            const int j1 = jb + 8, j2 = jb + 16;
            int2 e0 = make_int2(0, 0), e1 = make_int2(0, 0), e2 = make_int2(0, 0);
            if (jb < je) e0 = srec[jb];
            if (j1 < je) e1 = srec[j1];
            if (j2 < je) e2 = srec[j2];
            int4 z0 = make_int4(0,0,0,0), z1 = make_int4(0,0,0,0), z2 = make_int4(0,0,0,0);
            if (jb < je) z0 = Zq[(size_t)(e0.x & 0xFFFF) * 8 + q];
            if (j1 < je) z1 = Zq[(size_t)(e1.x & 0xFFFF) * 8 + q];
            if (j2 < je) z2 = Zq[(size_t)(e2.x & 0xFFFF) * 8 + q];
            FMA8(alo[r], ahi[r], __int_as_float(e0.y), z0);
            FMA8(alo[r], ahi[r], __int_as_float(e1.y), z1);
            FMA8(alo[r], ahi[r], __int_as_float(e2.y), z2);
            for (int j = j2 + 8; j < je; j += 8) {    // tail (deg > 24)
                int2 e = srec[j];
                int4 zz = Zq[(size_t)(e.x & 0xFFFF) * 8 + q];
                FMA8(alo[r], ahi[r], __int_as_float(e.y), zz);
            }
        }
        __syncthreads();
    }

    // reduce the 8 slots + store (8 lanes x 32 B = coalesced 256 B row)
    const int node0 = b * BKT + wv * 8;
#pragma unroll
    for (int r = 0; r < 8; ++r) {
        float4 lo = alo[r], hi = ahi[r];
#pragma unroll
        for (int off = 32; off >= 8; off >>= 1) {
            lo.x += __shfl_down(lo.x, off, 64);
            lo.y += __shfl_down(lo.y, off, 64);
            lo.z += __shfl_down(lo.z, off, 64);
            lo.w += __shfl_down(lo.w, off, 64);
            hi.x += __shfl_down(hi.x, off, 64);
            hi.y += __shfl_down(hi.y, off, 64);
            hi.z += __shfl_down(hi.z, off, 64);
            hi.w += __shfl_down(hi.w, off, 64);
        }
        int node = node0 + r;
        if (lane < 8 && node < N) {
            float4 o0, o1;
            o0.x = fmaxf(lo.x, 0.f); o0.y = fmaxf(lo.y, 0.f);
            o0.z = fmaxf(lo.z, 0.f); o0.w = fmaxf(lo.w, 0.f);
            o1.x = fmaxf(hi.x, 0.f); o1.y = fmaxf(hi.y, 0.f);
            o1.z = fmaxf(hi.z, 0.f); o1.w = fmaxf(hi.w, 0.f);
            float4* orow = reinterpret_cast<float4*>(out) + (size_t)node * 16 + lane * 2;
            orow[0] = o0;
            orow[1] = o1;
        }
    }
#undef FMA8
}

// ---------------------------------------------------------------------------
extern "C" void kernel_launch(void* const* d_in, const int* in_sizes, int n_in,
                              void* d_out, int out_size, void* d_ws, size_t ws_size,
                              hipStream_t stream)
{
    const float* emb  = (const float*)d_in[0];  // [N, 64]
    const int*   esrc = (const int*)  d_in[1];  // [E]
    const int*   edst = (const int*)  d_in[2];  // [E]
    const float* ew   = (const float*)d_in[3];  // [E]
    const float* W    = (const float*)d_in[4];  // [64, 64]
    float*       out  = (float*)d_out;          // [N, 64]

    const int N = in_sizes[0] / D;
    const int E = in_sizes[1];

    const int NB    = (N + BKT - 1) / BKT;   // 1563 buckets
    const int NC    = (E + CH - 1) / CH;     // 196 chunks
    const int M     = NB * NC;               // 306,348
    const int units = (M + SU - 1) / SU;     // 150 <= 256
    const int Mpad  = units * SU;
    const int gemmTiles = (N + 63) / 64;     // 782

    // Workspace (~15.2 MB), all segments 16 B aligned.
    char* p = (char*)d_ws;
    __hip_bfloat16* Zb = (__hip_bfloat16*)p;  p += (size_t)N * D * 2;   // 6.4 MB
    int*  histG    = (int*)p;                 p += (size_t)Mpad * 4;    // 1.2 MB
    int*  offsets  = (int*)p;                 p += (size_t)Mpad * 4;    // 1.2 MB
    int*  partials = (int*)p;                 p += 256 * 4;
    int2* csr      = (int2*)p;                                          // 6.4 MB

    gemm_part<<<gemmTiles + NC, 256, 0, stream>>>(
        emb, W, Zb, edst, histG, N, E, NB, NC, gemmTiles);

    scan_hist<<<units, 256, 0, stream>>>(histG, offsets, partials, M);

    scan_partials_k<<<1, 256, 0, stream>>>(partials, units);

    scatter_bkt<<<NC, 256, 0, stream>>>(
        esrc, edst, ew, offsets, partials, csr, E, NB, NC);

    aggregate<<<NB, 256, 0, stream>>>(
        Zb, csr, offsets, partials, out, N, NB, NC);
}